// Round 12
// baseline (50.319 us; speedup 1.0000x reference)
//
#include <hip/hip_runtime.h>

typedef unsigned short u16;
typedef __bf16 bf16x8 __attribute__((ext_vector_type(8)));
typedef float f32x4 __attribute__((ext_vector_type(4)));

#define B_   16
#define H_   56
#define W_   56
#define C_   128
#define OH_  54
#define OW_  54
#define NF_  256
#define KF_  1152           // C_*9
#define M_   46656          // B_*OH_*OW_
#define NNZ_ 58982

#define XB_ELEMS (B_*H_*W_*C_)       // 6422528
#define WT_ELEMS (KF_*NF_)           // 294912, flat [k/8][col][8] image

__device__ __forceinline__ u16 f2bf(float f) {
    unsigned u = __float_as_uint(f);
    u += 0x7FFFu + ((u >> 16) & 1u);
    return (u16)(u >> 16);
}

__device__ __forceinline__ void gload16(const void* g, void* l) {
    __builtin_amdgcn_global_load_lds(
        (const __attribute__((address_space(1))) unsigned int*)g,
        (__attribute__((address_space(3))) unsigned int*)l,
        16, 0, 0);
}

// ---- kernel 1: x f32 -> bf16 (8/thread) + fused zeroing of wt ----
__global__ __launch_bounds__(256) void cvt_x_kernel(const float* __restrict__ x,
                                                    u16* __restrict__ xb,
                                                    u16* __restrict__ wt) {
    if (blockIdx.x < 144) {
        uint4 z = {0u, 0u, 0u, 0u};
        ((uint4*)wt)[blockIdx.x * 256 + threadIdx.x] = z;
    }
    int i = (blockIdx.x * 256 + threadIdx.x) * 8;
    float4 v0 = *(const float4*)(x + i);
    float4 v1 = *(const float4*)(x + i + 4);
    union { u16 u[8]; uint4 v; } r;
    r.u[0] = f2bf(v0.x); r.u[1] = f2bf(v0.y); r.u[2] = f2bf(v0.z); r.u[3] = f2bf(v0.w);
    r.u[4] = f2bf(v1.x); r.u[5] = f2bf(v1.y); r.u[6] = f2bf(v1.z); r.u[7] = f2bf(v1.w);
    *(uint4*)(xb + i) = r.v;
}

// ---- kernel 2: scatter sparse values into W image [k/8][col][8] ----
__global__ __launch_bounds__(256) void scatter_kernel(const float* __restrict__ kv,
                                                      const int* __restrict__ idx,
                                                      u16* __restrict__ wt) {
    int t = blockIdx.x * 256 + threadIdx.x;
    if (t >= NNZ_) return;
    int k   = idx[2*t];      // row in [0,1152)
    int col = idx[2*t + 1];  // col in [0,256)
    wt[(k >> 3) * 2048 + col * 8 + (k & 7)] = f2bf(kv[t]);
}

// ---- kernel 3: 192x256-tile implicit GEMM (FLOP/staged-byte = 109.7) ----
// grid 243 = M/192 EXACT -> 1 block/CU single-shot, no B re-staging waves.
// 512 thr = 8 waves, wave tile 96x64 (wr=w>>2, wc=w&3), BK=64 -> 18 phases.
// LDS dbuf: A 2x24KB [row][chunk^(row&7)][8], B 2x32KB [chunk][col][8].
// Uniform staging: 3 A + 4 B gload_lds per thread per phase -> counted
// vmcnt(7) (next tile's 7 loads stay in flight; never drains mid-loop).
// Per phase per SIMD: 2 waves x 48 MFMA = 1863 cyc vs ~950 cyc staging
// ingest -> MFMA-bound (previous rounds: 64x256 tile was ingest-bound at
// ~24% MfmaUtil cap).
__global__ __launch_bounds__(512, 2) void spconv_gemm(const u16* __restrict__ xb,
                                                      const u16* __restrict__ wt,
                                                      const float* __restrict__ bias,
                                                      float* __restrict__ out) {
    __shared__ __align__(16) u16 As[2][12288];   // 2 x 24 KB
    __shared__ __align__(16) u16 Bs[2][16384];   // 2 x 32 KB

    const int t    = threadIdx.x;     // 0..511
    const int l    = t & 63;
    const int w    = t >> 6;          // wave 0..7
    const int r16  = l & 15;
    const int ks   = l >> 4;          // 0..3
    const int wr   = w >> 2;          // 0..1 (96-row half)
    const int wc   = w & 3;           // 0..3 (64-col quarter)
    const int m0   = blockIdx.x * 192;

    // A staging: thread t stages cells t, t+512, t+1024 of the 1536-cell
    // [row 192][chunk 8] tile -> rows r0, r0+64, r0+128, slot sd = t&7.
    // Source chunk = sd ^ (row&7)  (row&7 identical for the 3 rows).
    const int r0  = t >> 3;
    const int sd  = t & 7;
    const int kco = (sd ^ (r0 & 7)) * 8;          // elem offset in 64-k window
    const u16* a_base[3];
#pragma unroll
    for (int j = 0; j < 3; ++j) {
        int mg  = m0 + r0 + j * 64;
        int bb  = mg / (OH_ * OW_);
        int rem = mg % (OH_ * OW_);
        int ii  = rem / OW_;
        int jj  = rem % OW_;
        a_base[j] = xb + ((bb * H_ + ii) * W_ + jj) * C_;
    }

    f32x4 acc[6][4];
    const f32x4 zz = {0.f, 0.f, 0.f, 0.f};
#pragma unroll
    for (int i = 0; i < 6; ++i)
#pragma unroll
        for (int j = 0; j < 4; ++j) acc[i][j] = zz;

#define ISSUE(kt, bi) do {                                                  \
    int g_  = (kt) >> 1;                                                    \
    int di_ = (g_ * 11) >> 5;                                               \
    int dj_ = g_ - 3 * di_;                                                 \
    int apix_ = (di_ * W_ + dj_) * C_ + ((kt) & 1) * 64 + kco;              \
    gload16(a_base[0] + apix_, &As[bi][t * 8]);                             \
    gload16(a_base[1] + apix_, &As[bi][t * 8 + 4096]);                      \
    gload16(a_base[2] + apix_, &As[bi][t * 8 + 8192]);                      \
    const u16* bsrc_ = wt + (kt) * 16384 + t * 8;                           \
    gload16(bsrc_,         &Bs[bi][t * 8]);                                 \
    gload16(bsrc_ + 4096,  &Bs[bi][t * 8 + 4096]);                          \
    gload16(bsrc_ + 8192,  &Bs[bi][t * 8 + 8192]);                          \
    gload16(bsrc_ + 12288, &Bs[bi][t * 8 + 12288]);                         \
} while (0)

// per h-half: 6 A-frag + 4 B-frag ds_read_b128, then 24 MFMAs
#define COMPUTE(bi) do {                                                    \
    _Pragma("unroll")                                                       \
    for (int h = 0; h < 2; ++h) {                                           \
        const int chs_ = ((h * 4 + ks) ^ (r16 & 7)) * 8;                    \
        bf16x8 af_[6];                                                      \
        _Pragma("unroll")                                                   \
        for (int mf = 0; mf < 6; ++mf)                                      \
            af_[mf] = *(const bf16x8*)(&As[bi][(wr * 96 + mf * 16 + r16) * 64 + chs_]); \
        _Pragma("unroll")                                                   \
        for (int nf = 0; nf < 4; ++nf) {                                    \
            bf16x8 bf_ = *(const bf16x8*)(&Bs[bi][((h * 4 + ks) * 256 + wc * 64 + nf * 16 + r16) * 8]); \
            _Pragma("unroll")                                               \
            for (int mf = 0; mf < 6; ++mf)                                  \
                acc[mf][nf] = __builtin_amdgcn_mfma_f32_16x16x32_bf16(      \
                    af_[mf], bf_, acc[mf][nf], 0, 0, 0);                    \
        }                                                                   \
    }                                                                       \
} while (0)

#define WAITVM(n) asm volatile("s_waitcnt vmcnt(" #n ")" ::: "memory")
#define BAR() do { __builtin_amdgcn_s_barrier();                            \
                   asm volatile("" ::: "memory"); } while (0)

    // prologue: tiles 0,1 in flight (7 loads each per thread)
    ISSUE(0, 0);
    ISSUE(1, 1);

    // main loop: 18 K-steps; iters 0..15 issue tiles 2..17
#pragma unroll
    for (int k = 0; k < 16; ++k) {
        WAITVM(7);            // tile k landed; tile k+1's 7 loads in flight
        BAR();                // staging visible to all waves
        COMPUTE(k & 1);
        BAR();                // all waves done reading buf[k&1]
        ISSUE(k + 2, k & 1);
    }
    // tail: tiles 16, 17 (no further issues)
    WAITVM(7); BAR(); COMPUTE(0);
    WAITVM(0); BAR(); COMPUTE(1);

#undef ISSUE
#undef COMPUTE
#undef WAITVM
#undef BAR

    // epilogue: C/D layout col = lane&15, row = (lane>>4)*4 + reg (m89-verified)
#pragma unroll
    for (int nf = 0; nf < 4; ++nf) {
        int col  = wc * 64 + nf * 16 + r16;
        float bv = bias[col];
#pragma unroll
        for (int mf = 0; mf < 6; ++mf) {
#pragma unroll
            for (int rr = 0; rr < 4; ++rr) {
                int row = m0 + wr * 96 + mf * 16 + ks * 4 + rr;
                float v = acc[mf][nf][rr] + bv;
                out[row * NF_ + col] = fmaxf(v, 0.f);
            }
        }
    }
}

extern "C" void kernel_launch(void* const* d_in, const int* in_sizes, int n_in,
                              void* d_out, int out_size, void* d_ws, size_t ws_size,
                              hipStream_t stream) {
    const float* x    = (const float*)d_in[0];
    const float* kv   = (const float*)d_in[1];
    const float* bias = (const float*)d_in[2];
    const int*   idx  = (const int*)d_in[3];
    float* out = (float*)d_out;

    u16* xb  = (u16*)d_ws;
    u16* wtp = (u16*)((char*)d_ws + (size_t)XB_ELEMS * 2);

    cvt_x_kernel<<<XB_ELEMS / (256 * 8), 256, 0, stream>>>(x, xb, wtp);
    scatter_kernel<<<(NNZ_ + 255) / 256, 256, 0, stream>>>(kv, idx, wtp);
    spconv_gemm<<<M_ / 192, 512, 0, stream>>>(xb, wtp, bias, out);
}

// Round 13
// 47.462 us; speedup vs baseline: 1.0602x; 1.0602x over previous
//
#include <hip/hip_runtime.h>

typedef unsigned short u16;
typedef __bf16 bf16x8 __attribute__((ext_vector_type(8)));
typedef float f32x4 __attribute__((ext_vector_type(4)));

#define B_   16
#define H_   56
#define W_   56
#define C_   128
#define OH_  54
#define OW_  54
#define NF_  256
#define KF_  1152           // C_*9
#define M_   46656          // B_*OH_*OW_
#define NNZ_ 58982

#define XB_ELEMS (B_*H_*W_*C_)       // 6422528
#define WT_ELEMS (KF_*NF_)           // 294912, flat [k/8][col][8] image

__device__ __forceinline__ u16 f2bf(float f) {
    unsigned u = __float_as_uint(f);
    u += 0x7FFFu + ((u >> 16) & 1u);
    return (u16)(u >> 16);
}

__device__ __forceinline__ void gload16(const void* g, void* l) {
    __builtin_amdgcn_global_load_lds(
        (const __attribute__((address_space(1))) unsigned int*)g,
        (__attribute__((address_space(3))) unsigned int*)l,
        16, 0, 0);
}

// ---- kernel 1: x f32 -> bf16 (8/thread) + fused zeroing of wt ----
__global__ __launch_bounds__(256) void cvt_x_kernel(const float* __restrict__ x,
                                                    u16* __restrict__ xb,
                                                    u16* __restrict__ wt) {
    if (blockIdx.x < 144) {
        uint4 z = {0u, 0u, 0u, 0u};
        ((uint4*)wt)[blockIdx.x * 256 + threadIdx.x] = z;
    }
    int i = (blockIdx.x * 256 + threadIdx.x) * 8;
    float4 v0 = *(const float4*)(x + i);
    float4 v1 = *(const float4*)(x + i + 4);
    union { u16 u[8]; uint4 v; } r;
    r.u[0] = f2bf(v0.x); r.u[1] = f2bf(v0.y); r.u[2] = f2bf(v0.z); r.u[3] = f2bf(v0.w);
    r.u[4] = f2bf(v1.x); r.u[5] = f2bf(v1.y); r.u[6] = f2bf(v1.z); r.u[7] = f2bf(v1.w);
    *(uint4*)(xb + i) = r.v;
}

// ---- kernel 2: scatter sparse values into W image [k/8][col][8] ----
__global__ __launch_bounds__(256) void scatter_kernel(const float* __restrict__ kv,
                                                      const int* __restrict__ idx,
                                                      u16* __restrict__ wt) {
    int t = blockIdx.x * 256 + threadIdx.x;
    if (t >= NNZ_) return;
    int k   = idx[2*t];      // row in [0,1152)
    int col = idx[2*t + 1];  // col in [0,256)
    wt[(k >> 3) * 2048 + col * 8 + (k & 7)] = f2bf(kv[t]);
}

// ---- kernel 3: 192x256 implicit GEMM, m201-style 8-barrier 4-phase K-steps ----
// grid 243 (exact), 512 thr = 8 waves (2M x 4N), per-wave 96x64, BK=64.
// LDS dbuf: A 2x24KB [row192][chunk8^row-xor][8], B 2x32KB [chunk8][col256][8].
// K-step = 4 phases (h-half x mf-triple): {[vmcnt]; bar; ds_read 3-7; issue
// 1-2 gload_lds of tile k+1; bar; lgkm0; sched_bar; setprio1; 12 MFMA; prio0}.
// Ledger (7 loads/tile in order a0,a1,a2,b0,b1,b2,b3): P0 needs a0..b1 ->
// vmcnt(2); P2 needs b2,b3 -> vmcnt(4) (4 = k+1 issues so far). Never 0.
__global__ __launch_bounds__(512) void spconv_gemm(const u16* __restrict__ xb,
                                                   const u16* __restrict__ wt,
                                                   const float* __restrict__ bias,
                                                   float* __restrict__ out) {
    __shared__ __align__(16) u16 As[2][12288];   // 2 x 24 KB
    __shared__ __align__(16) u16 Bs[2][16384];   // 2 x 32 KB

    const int t    = threadIdx.x;     // 0..511
    const int l    = t & 63;
    const int w    = t >> 6;          // wave 0..7
    const int r16  = l & 15;
    const int ks   = l >> 4;          // 0..3
    const int wr   = w >> 2;          // 0..1 (96-row half)
    const int wc   = w & 3;           // 0..3 (64-col quarter)

    // bijective XCD swizzle (nwg=243 -> m204)
    const int nwg = gridDim.x;
    const int q = nwg >> 3, rr_ = nwg & 7;
    const int xcd = blockIdx.x & 7, inner = blockIdx.x >> 3;
    const int wg = (xcd < rr_ ? xcd * (q + 1) : rr_ * (q + 1) + (xcd - rr_) * q) + inner;
    const int m0 = wg * 192;

    // A staging: thread t stages rows r0, r0+64, r0+128 (slot sd = t&7);
    // source chunk = sd ^ (r0&7) (row&7 identical for the 3 rows).
    const int r0  = t >> 3;
    const int sd  = t & 7;
    const int kco = (sd ^ (r0 & 7)) * 8;
    const u16* a_base[3];
#pragma unroll
    for (int j = 0; j < 3; ++j) {
        int mg  = m0 + r0 + j * 64;
        int bb  = mg / (OH_ * OW_);
        int rem = mg % (OH_ * OW_);
        int ii  = rem / OW_;
        int jj  = rem % OW_;
        a_base[j] = xb + ((bb * H_ + ii) * W_ + jj) * C_;
    }

    f32x4 acc[6][4];
    const f32x4 zz = {0.f, 0.f, 0.f, 0.f};
#pragma unroll
    for (int i = 0; i < 6; ++i)
#pragma unroll
        for (int j = 0; j < 4; ++j) acc[i][j] = zz;

// fragment reads (chunk XOR matches staging source swizzle; R12-verified)
#define RA_(bi,h,mf) (*(const bf16x8*)(&As[bi][(wr * 96 + (mf) * 16 + r16) * 64 + (((h) * 4 + ks) ^ (r16 & 7)) * 8]))
#define RB_(bi,h,nf) (*(const bf16x8*)(&Bs[bi][(((h) * 4 + ks) * 256 + wc * 64 + (nf) * 16 + r16) * 8]))

#define IA_(kn,bj,j) do {                                                   \
    int g_  = (kn) >> 1;                                                    \
    int di_ = (g_ * 11) >> 5;                                               \
    int dj_ = g_ - 3 * di_;                                                 \
    gload16(a_base[j] + (di_ * W_ + dj_) * C_ + ((kn) & 1) * 64 + kco,      \
            &As[bj][t * 8 + (j) * 4096]);                                   \
} while (0)
#define IB_(kn,bj,j) gload16(wt + (kn) * 16384 + (j) * 4096 + t * 8,        \
                             &Bs[bj][t * 8 + (j) * 4096])

#define WAITVM(n) asm volatile("s_waitcnt vmcnt(" #n ")" ::: "memory")
#define LG0()     asm volatile("s_waitcnt lgkmcnt(0)" ::: "memory")
#define SB0()     __builtin_amdgcn_sched_barrier(0)
#define BAR()     do { __builtin_amdgcn_s_barrier();                        \
                       asm volatile("" ::: "memory"); } while (0)

#define MM12(A0,A1,A2,MB,B0,B1,B2,B3) do {                                  \
    acc[(MB)+0][0] = __builtin_amdgcn_mfma_f32_16x16x32_bf16(A0, B0, acc[(MB)+0][0], 0, 0, 0); \
    acc[(MB)+1][0] = __builtin_amdgcn_mfma_f32_16x16x32_bf16(A1, B0, acc[(MB)+1][0], 0, 0, 0); \
    acc[(MB)+2][0] = __builtin_amdgcn_mfma_f32_16x16x32_bf16(A2, B0, acc[(MB)+2][0], 0, 0, 0); \
    acc[(MB)+0][1] = __builtin_amdgcn_mfma_f32_16x16x32_bf16(A0, B1, acc[(MB)+0][1], 0, 0, 0); \
    acc[(MB)+1][1] = __builtin_amdgcn_mfma_f32_16x16x32_bf16(A1, B1, acc[(MB)+1][1], 0, 0, 0); \
    acc[(MB)+2][1] = __builtin_amdgcn_mfma_f32_16x16x32_bf16(A2, B1, acc[(MB)+2][1], 0, 0, 0); \
    acc[(MB)+0][2] = __builtin_amdgcn_mfma_f32_16x16x32_bf16(A0, B2, acc[(MB)+0][2], 0, 0, 0); \
    acc[(MB)+1][2] = __builtin_amdgcn_mfma_f32_16x16x32_bf16(A1, B2, acc[(MB)+1][2], 0, 0, 0); \
    acc[(MB)+2][2] = __builtin_amdgcn_mfma_f32_16x16x32_bf16(A2, B2, acc[(MB)+2][2], 0, 0, 0); \
    acc[(MB)+0][3] = __builtin_amdgcn_mfma_f32_16x16x32_bf16(A0, B3, acc[(MB)+0][3], 0, 0, 0); \
    acc[(MB)+1][3] = __builtin_amdgcn_mfma_f32_16x16x32_bf16(A1, B3, acc[(MB)+1][3], 0, 0, 0); \
    acc[(MB)+2][3] = __builtin_amdgcn_mfma_f32_16x16x32_bf16(A2, B3, acc[(MB)+2][3], 0, 0, 0); \
} while (0)

#define SP(n) __builtin_amdgcn_s_setprio(n)

// one K-step (4 phases). DOISS: stage tile kn=k+1. LASTW: P2 wait (4 or 0).
#define STEP(bi_, kn_, DOISS, P2W) do {                                     \
    const int bj_ = (bi_) ^ 1;                                              \
    /* P0 (h=0, mf 0-2) */                                                  \
    WAITVM(2); BAR();                                                       \
    {                                                                       \
    bf16x8 bf0 = RB_(bi_,0,0), bf1 = RB_(bi_,0,1),                          \
           bf2 = RB_(bi_,0,2), bf3 = RB_(bi_,0,3);                          \
    bf16x8 a0 = RA_(bi_,0,0), a1 = RA_(bi_,0,1), a2 = RA_(bi_,0,2);         \
    if (DOISS) { IA_(kn_, bj_, 0); IA_(kn_, bj_, 1); }                      \
    BAR(); LG0(); SB0();                                                    \
    SP(1); MM12(a0, a1, a2, 0, bf0, bf1, bf2, bf3); SP(0);                  \
    /* P1 (h=0, mf 3-5) */                                                  \
    BAR();                                                                  \
    bf16x8 a3 = RA_(bi_,0,3), a4 = RA_(bi_,0,4), a5 = RA_(bi_,0,5);         \
    if (DOISS) { IA_(kn_, bj_, 2); IB_(kn_, bj_, 0); }                      \
    BAR(); LG0(); SB0();                                                    \
    SP(1); MM12(a3, a4, a5, 3, bf0, bf1, bf2, bf3); SP(0);                  \
    }                                                                       \
    /* P2 (h=1, mf 0-2) */                                                  \
    WAITVM(P2W); BAR();                                                     \
    {                                                                       \
    bf16x8 bf0 = RB_(bi_,1,0), bf1 = RB_(bi_,1,1),                          \
           bf2 = RB_(bi_,1,2), bf3 = RB_(bi_,1,3);                          \
    bf16x8 a0 = RA_(bi_,1,0), a1 = RA_(bi_,1,1), a2 = RA_(bi_,1,2);         \
    if (DOISS) { IB_(kn_, bj_, 1); IB_(kn_, bj_, 2); }                      \
    BAR(); LG0(); SB0();                                                    \
    SP(1); MM12(a0, a1, a2, 0, bf0, bf1, bf2, bf3); SP(0);                  \
    /* P3 (h=1, mf 3-5) */                                                  \
    BAR();                                                                  \
    bf16x8 a3 = RA_(bi_,1,3), a4 = RA_(bi_,1,4), a5 = RA_(bi_,1,5);         \
    if (DOISS) { IB_(kn_, bj_, 3); }                                        \
    BAR(); LG0(); SB0();                                                    \
    SP(1); MM12(a3, a4, a5, 3, bf0, bf1, bf2, bf3); SP(0);                  \
    }                                                                       \
} while (0)

    // prologue: tile 0 in flight (7 loads, order a0,a1,a2,b0,b1,b2,b3)
    IA_(0, 0, 0); IA_(0, 0, 1); IA_(0, 0, 2);
    IB_(0, 0, 0); IB_(0, 0, 1); IB_(0, 0, 2); IB_(0, 0, 3);

    // steps 0..16 stage the next tile; step 17 drains
#pragma unroll
    for (int k = 0; k < 16; k += 2) {
        STEP(0, k + 1, 1, 4);
        STEP(1, k + 2, 1, 4);
    }
    STEP(0, 17, 1, 4);   // k=16
    STEP(1, 18, 0, 0);   // k=17 (no issues; P2 drains to 0)

#undef RA_
#undef RB_
#undef IA_
#undef IB_
#undef WAITVM
#undef LG0
#undef SB0
#undef BAR
#undef MM12
#undef SP
#undef STEP

    // epilogue: C/D layout col = lane&15, row = (lane>>4)*4 + reg (m89-verified)
#pragma unroll
    for (int nf = 0; nf < 4; ++nf) {
        int col  = wc * 64 + nf * 16 + r16;
        float bv = bias[col];
#pragma unroll
        for (int mf = 0; mf < 6; ++mf) {
#pragma unroll
            for (int rg = 0; rg < 4; ++rg) {
                int row = m0 + wr * 96 + mf * 16 + ks * 4 + rg;
                float v = acc[mf][nf][rg] + bv;
                out[row * NF_ + col] = fmaxf(v, 0.f);
            }
        }
    }
}

extern "C" void kernel_launch(void* const* d_in, const int* in_sizes, int n_in,
                              void* d_out, int out_size, void* d_ws, size_t ws_size,
                              hipStream_t stream) {
    const float* x    = (const float*)d_in[0];
    const float* kv   = (const float*)d_in[1];
    const float* bias = (const float*)d_in[2];
    const int*   idx  = (const int*)d_in[3];
    float* out = (float*)d_out;

    u16* xb  = (u16*)d_ws;
    u16* wtp = (u16*)((char*)d_ws + (size_t)XB_ELEMS * 2);

    cvt_x_kernel<<<XB_ELEMS / (256 * 8), 256, 0, stream>>>(x, xb, wtp);
    scatter_kernel<<<(NNZ_ + 255) / 256, 256, 0, stream>>>(kv, idx, wtp);
    spconv_gemm<<<M_ / 192, 512, 0, stream>>>(xb, wtp, bias, out);
}